// Round 7
// baseline (4622.378 us; speedup 1.0000x reference)
//
#include <hip/hip_runtime.h>
#include <math.h>

// Problem dims
#define NB   16
#define NC   1024
#define ND   256
#define NT_  9
#define TDIM 32

typedef _Float16 half8 __attribute__((ext_vector_type(8)));
typedef _Float16 half4v __attribute__((ext_vector_type(4)));
typedef float f32x4 __attribute__((ext_vector_type(4)));

#define GLL(gp, lp)                                                            \
  __builtin_amdgcn_global_load_lds(                                            \
      (const __attribute__((address_space(1))) void*)(gp),                     \
      (__attribute__((address_space(3))) void*)(lp), 16, 0, 0)

#define MFMA16(A, B, C) __builtin_amdgcn_mfma_f32_16x16x32_f16(A, B, C, 0, 0, 0)

#define WBAR()                                                                 \
  do {                                                                         \
    asm volatile("s_waitcnt vmcnt(0)" ::: "memory");                           \
    __builtin_amdgcn_s_barrier();                                              \
  } while (0)

// ---------------------------------------------------------------------------
__global__ __launch_bounds__(256) void k_copy_h0(const float* __restrict__ h0,
                                                 float* __restrict__ out) {
  size_t idx = (size_t)blockIdx.x * blockDim.x + threadIdx.x;
  size_t fe = idx * 4;
  size_t b = fe / ((size_t)NC * ND);
  size_t rem = fe % ((size_t)NC * ND);
  float4 v = *(const float4*)(h0 + fe);
  *(float4*)(out + (b * NT_) * (size_t)NC * ND + rem) = v;
}

// ---------------------------------------------------------------------------
__global__ __launch_bounds__(256) void k_deg(const float* __restrict__ adj,
                                             float* __restrict__ invdeg) {
  int wave = threadIdx.x >> 6;
  int lane = threadIdx.x & 63;
  int row = blockIdx.x * 4 + wave;
  const float* p = adj + (size_t)row * NC;
  float s = 0.f;
#pragma unroll
  for (int q = 0; q < 4; ++q) {
    float4 v = *(const float4*)(p + q * 256 + lane * 4);
    s += v.x + v.y + v.z + v.w;
  }
#pragma unroll
  for (int off = 32; off; off >>= 1) s += __shfl_down(s, off);
  if (lane == 0) invdeg[row] = 1.f / fmaxf(s, 1.f);
}

// ---------------------------------------------------------------------------
__global__ __launch_bounds__(256) void k_split_adj(const float* __restrict__ adj,
                                                   _Float16* __restrict__ aH) {
  size_t i4 = (size_t)blockIdx.x * 256 + threadIdx.x;
  float4 v = *(const float4*)(adj + i4 * 4);
  half4v h;
  h[0] = (_Float16)v.x; h[1] = (_Float16)v.y;
  h[2] = (_Float16)v.z; h[3] = (_Float16)v.w;
  *(half4v*)(aH + i4 * 4) = h;
}

// ---------------------------------------------------------------------------
__global__ __launch_bounds__(256) void k_split_w(const float* __restrict__ W1,
                                                 const float* __restrict__ W2,
                                                 _Float16* __restrict__ W1TH,
                                                 _Float16* __restrict__ W1TL,
                                                 _Float16* __restrict__ W2TH,
                                                 _Float16* __restrict__ W2TL) {
  int o = blockIdx.x * 256 + threadIdx.x;
  if (o < 256 * 512) {
    int n = o >> 9, k = o & 511;
    float v = W1[(size_t)k * ND + n];
    _Float16 h = (_Float16)v;
    W1TH[o] = h;
    W1TL[o] = (_Float16)(v - (float)h);
  } else {
    int o2 = o - 256 * 512;
    int n = o2 >> 8, k = o2 & 255;
    float v = W2[(size_t)k * ND + n];
    _Float16 h = (_Float16)v;
    W2TH[o2] = h;
    W2TL[o2] = (_Float16)(v - (float)h);
  }
}

// ---------------------------------------------------------------------------
// one-time: h0 -> hH/hL [b][c][d] + hT [b][d][c] (hi only)
__global__ __launch_bounds__(256) void k_htsplit(const float* __restrict__ src,
                                                 _Float16* __restrict__ hH,
                                                 _Float16* __restrict__ hL,
                                                 _Float16* __restrict__ hT) {
  __shared__ _Float16 tile[64][65];
  int b = blockIdx.z, c0 = blockIdx.x * 64, d0 = blockIdx.y * 64;
  int t = threadIdx.x;
#pragma unroll
  for (int it = 0; it < 16; ++it) {
    int e = it * 256 + t;
    int cl = e >> 6, dl = e & 63;
    float v = src[((size_t)b * NC + c0 + cl) * ND + d0 + dl];
    _Float16 h = (_Float16)v;
    _Float16 lo = (_Float16)(v - (float)h);
    size_t ni = ((size_t)b * NC + c0 + cl) * ND + d0 + dl;
    hH[ni] = h;
    hL[ni] = lo;
    tile[dl][cl] = h;
  }
  __syncthreads();
#pragma unroll
  for (int it = 0; it < 16; ++it) {
    int e = it * 256 + t;
    int dl = e >> 6, cl = e & 63;
    size_t ti = ((size_t)b * ND + d0 + dl) * NC + c0 + cl;
    hT[ti] = tile[dl][cl];
  }
}

// ---------------------------------------------------------------------------
// k_stage: one fused RK4 stage. grid 512 (swizzled: batch -> one XCD),
// 512 thr = 8 waves (2m x 4n), tile 32 rows x 256 cols.
// phase0: agg = invdeg * adj@h   (K=1024, 1p; adj rows via direct frags,
//         hT panel LDS-staged)                     -> aggS (LDS, hi)
// phaseA: u = tanh([h|agg]@W1+b1eff) (K=512; h: 3p w/ direct lo-frags,
//         agg: 2p hi-only; W1-lo direct frags)     -> uS (LDS, hi)
// phaseB: f = u@W2+b2 (K=256, 2p; W2-lo direct frags)
// epilogue: RK4 update; writes hH/hL in place, hT ping-pong, traj out.
__global__ __launch_bounds__(512, 6) void k_stage(
    const _Float16* __restrict__ adjH,
    _Float16* __restrict__ hH, _Float16* __restrict__ hL,
    const _Float16* __restrict__ hTr, _Float16* __restrict__ hTw,
    const float* __restrict__ invdeg,
    const _Float16* __restrict__ W1TH, const _Float16* __restrict__ W1TL,
    const _Float16* __restrict__ W2TH, const _Float16* __restrict__ W2TL,
    const float* __restrict__ W1, const float* __restrict__ b1,
    const float* __restrict__ b2, const float* __restrict__ tg,
    int step, int stage, float* __restrict__ out, float* __restrict__ accws) {
  __shared__ __align__(16) _Float16 Bs[2][256 * 32];  // 32 KB (B-panel dbuf)
  __shared__ __align__(16) _Float16 POOL[8192];       // 16 KB aggS -> uS
  __shared__ float te_s[TDIM];
  __shared__ float b1s[256];

  const int tid = threadIdx.x;
  const int lane = tid & 63, wid = tid >> 6;
  const int wm = wid >> 2, wn = wid & 3;  // 2 x 4 waves
  const int g = lane >> 4, r = lane & 15;
  const int rg = g * 4;
  // swizzle: batch b's 32 blocks all have id % 8 == b % 8 (same XCD)
  const int p = blockIdx.x;
  const int b = ((p >> 3) >> 5) * 8 + (p & 7);
  const int mq = (p >> 3) & 31;

  const size_t abase = ((size_t)b * NC + mq * 32) * ND;
  const _Float16* B0 = hTr + (size_t)b * ND * NC;  // 256 rows, stride NC
  _Float16* aggS = POOL;
  _Float16* uS = POOL;  // alias; disjoint lifetimes

  f32x4 acc[4] = {};

  // B-panel staging: 256 rows x 32 k -> plane-major chunks [g][row][8]
#define STAGE_B(SRC, STRIDE, K0, BUF)                                          \
  do {                                                                         \
    _Pragma("unroll") for (int c = 0; c < 2; ++c) {                            \
      int e = c * 512 + tid;                                                   \
      int gg = e >> 8, n = e & 255;                                            \
      GLL((SRC) + (size_t)n * (STRIDE) + gg * 8 + (K0), &Bs[BUF][(size_t)e * 8]); \
    }                                                                          \
  } while (0)

  // ---- prologue ----
  STAGE_B(B0, NC, 0, 0);
  if (tid < 16) {
    float t0 = tg[step], t1 = tg[step + 1];
    float frac = (stage == 0) ? 0.f : ((stage == 3) ? 1.f : 0.5f);
    float t = t0 + frac * (t1 - t0);
    float f = expf(-logf(10000.f) * (float)tid / 16.f);
    te_s[tid] = sinf(t * f);
    te_s[tid + 16] = cosf(t * f);
  }
  __syncthreads();
  if (tid < 256) {
    float s = b1[tid];
#pragma unroll
    for (int q = 0; q < TDIM; ++q)
      s = fmaf(te_s[q], W1[(size_t)(512 + q) * ND + tid], s);
    b1s[tid] = s;
  }
  // ---- phase 0: K = 1024, single-product; A = adj rows (direct frags) ----
  const _Float16* adjRow =
      adjH + (size_t)(b * NC + mq * 32 + wm * 16 + r) * NC + g * 8;
  for (int t = 0; t < 32; ++t) {
    int cur = t & 1;
    half8 Af = *(const half8*)(adjRow + t * 32);
    if (t + 1 < 32) STAGE_B(B0, NC, (t + 1) * 32, cur ^ 1);
#pragma unroll
    for (int j = 0; j < 4; ++j) {
      half8 Bf = ((const half8*)Bs[cur])[g * 256 + wn * 64 + j * 16 + r];
      acc[j] = MFMA16(Af, Bf, acc[j]);
    }
    WBAR();
  }
  // ---- phase0 epilogue: invdeg scale -> aggS (hi only) ----
#pragma unroll
  for (int j = 0; j < 4; ++j) {
    int d = wn * 64 + j * 16 + r;
#pragma unroll
    for (int q = 0; q < 4; ++q) {
      int lr = wm * 16 + rg + q;
      float v = acc[j][q] * invdeg[b * NC + mq * 32 + lr];
      aggS[((d >> 3) * 32 + lr) * 8 + (d & 7)] = (_Float16)v;
    }
    acc[j] = (f32x4){0.f, 0.f, 0.f, 0.f};
  }
  STAGE_B(W1TH, 512, 0, 0);
  __syncthreads();
  // ---- phase A: K = 512 ([h | agg]); W1-lo via direct frags ----
  const _Float16* hHrow = hH + abase + (size_t)(wm * 16 + r) * ND + g * 8;
  const _Float16* hLrow = hL + abase + (size_t)(wm * 16 + r) * ND + g * 8;
  for (int t = 0; t < 16; ++t) {
    int cur = t & 1;
    int k0 = t * 32;
    half8 AH, AL;
    const bool hasL = (t < 8);
    if (hasL) {
      AH = *(const half8*)(hHrow + k0);
      AL = *(const half8*)(hLrow + k0);
    } else {
      AH = ((const half8*)aggS)[((t - 8) * 4 + g) * 32 + wm * 16 + r];
    }
    if (t + 1 < 16) STAGE_B(W1TH, 512, k0 + 32, cur ^ 1);
    const _Float16* W1TLb = W1TL + (size_t)(wn * 64 + r) * 512 + k0 + g * 8;
#pragma unroll
    for (int j = 0; j < 4; ++j) {
      half8 BH = ((const half8*)Bs[cur])[g * 256 + wn * 64 + j * 16 + r];
      half8 BL = *(const half8*)(W1TLb + (size_t)(j * 16) * 512);
      acc[j] = MFMA16(AH, BH, acc[j]);
      acc[j] = MFMA16(AH, BL, acc[j]);
      if (hasL) acc[j] = MFMA16(AL, BH, acc[j]);
    }
    WBAR();
  }
  // ---- transition: uS = tanh(acc + b1s) (aliases dead aggS) ----
#pragma unroll
  for (int j = 0; j < 4; ++j) {
    int col = wn * 64 + j * 16 + r;
#pragma unroll
    for (int q = 0; q < 4; ++q) {
      int row = wm * 16 + rg + q;
      float v = tanhf(acc[j][q] + b1s[col]);
      uS[((col >> 3) * 32 + row) * 8 + (col & 7)] = (_Float16)v;
    }
    acc[j] = (f32x4){0.f, 0.f, 0.f, 0.f};
  }
  STAGE_B(W2TH, 256, 0, 0);
  __syncthreads();
  // ---- phase B: K = 256 over u; W2-lo via direct frags ----
  for (int t = 0; t < 8; ++t) {
    int cur = t & 1;
    int k0 = t * 32;
    half8 Af = ((const half8*)uS)[(t * 4 + g) * 32 + wm * 16 + r];
    if (t + 1 < 8) STAGE_B(W2TH, 256, k0 + 32, cur ^ 1);
    const _Float16* W2TLb = W2TL + (size_t)(wn * 64 + r) * 256 + k0 + g * 8;
#pragma unroll
    for (int j = 0; j < 4; ++j) {
      half8 BH = ((const half8*)Bs[cur])[g * 256 + wn * 64 + j * 16 + r];
      half8 BL = *(const half8*)(W2TLb + (size_t)(j * 16) * 256);
      acc[j] = MFMA16(Af, BH, acc[j]);
      acc[j] = MFMA16(Af, BL, acc[j]);
    }
    WBAR();
  }
  // ---- RK4 epilogue ----
  const float t0 = tg[step], t1 = tg[step + 1];
  const float dt = t1 - t0;
  const float cs = (stage == 2) ? dt : 0.5f * dt;
#pragma unroll
  for (int j = 0; j < 4; ++j) {
    int col = wn * 64 + j * 16 + r;
    float bb2 = b2[col];
    int ii0 = mq * 32 + wm * 16 + rg;  // row in batch, multiple of 4
    size_t hrow = (((size_t)b * NT_ + step) * NC + ii0) * (size_t)ND + col;
    size_t wrow = ((size_t)b * NC + ii0) * (size_t)ND + col;
    float val[4];
#pragma unroll
    for (int q = 0; q < 4; ++q) {
      float f = acc[j][q] + bb2;
      float hb = out[hrow + (size_t)q * ND];
      size_t widx = wrow + (size_t)q * ND;
      if (stage == 0) {
        accws[widx] = f;
        val[q] = hb + cs * f;
      } else if (stage == 3) {
        float hn = hb + (dt / 6.f) * (accws[widx] + f);
        out[hrow + (size_t)NC * ND + (size_t)q * ND] = hn;  // traj[:,step+1]
        val[q] = hn;
      } else {
        accws[widx] += 2.f * f;
        val[q] = hb + cs * f;
      }
    }
    half4v th;
#pragma unroll
    for (int q = 0; q < 4; ++q) {
      _Float16 hh = (_Float16)val[q];
      th[q] = hh;
      size_t ni = ((size_t)b * NC + ii0 + q) * ND + col;
      hH[ni] = hh;
      hL[ni] = (_Float16)(val[q] - (float)hh);
    }
    size_t trow = ((size_t)b * ND + col) * NC + ii0;
    *(half4v*)(hTw + trow) = th;
  }
}

// ---------------------------------------------------------------------------
extern "C" void kernel_launch(void* const* d_in, const int* in_sizes, int n_in,
                              void* d_out, int out_size, void* d_ws, size_t ws_size,
                              hipStream_t stream) {
  const float* h0 = (const float*)d_in[0];
  const float* tg = (const float*)d_in[1];
  const float* adj = (const float*)d_in[2];
  const float* W1 = (const float*)d_in[3];
  const float* b1 = (const float*)d_in[4];
  const float* W2 = (const float*)d_in[5];
  const float* b2 = (const float*)d_in[6];
  float* out = (float*)d_out;

  const size_t CD = (size_t)NC * ND;  // 262144
  char* w = (char*)d_ws;
  float* invdeg = (float*)w;     w += (size_t)16384 * 4;
  float* accws = (float*)w;      w += (size_t)NB * CD * 4;
  _Float16* adjH = (_Float16*)w; w += (size_t)NB * NC * NC * 2;
  _Float16* hH = (_Float16*)w;   w += (size_t)NB * CD * 2;
  _Float16* hL = (_Float16*)w;   w += (size_t)NB * CD * 2;
  _Float16* hTa = (_Float16*)w;  w += (size_t)NB * CD * 2;
  _Float16* hTb = (_Float16*)w;  w += (size_t)NB * CD * 2;
  _Float16* W1TH = (_Float16*)w; w += (size_t)256 * 512 * 2;
  _Float16* W1TL = (_Float16*)w; w += (size_t)256 * 512 * 2;
  _Float16* W2TH = (_Float16*)w; w += (size_t)256 * 256 * 2;
  _Float16* W2TL = (_Float16*)w; w += (size_t)256 * 256 * 2;

  k_copy_h0<<<dim3(4096), dim3(256), 0, stream>>>(h0, out);
  k_deg<<<dim3(4096), dim3(256), 0, stream>>>(adj, invdeg);
  k_split_adj<<<dim3(16384), dim3(256), 0, stream>>>(adj, adjH);
  k_split_w<<<dim3(768), dim3(256), 0, stream>>>(W1, W2, W1TH, W1TL, W2TH, W2TL);
  k_htsplit<<<dim3(16, 4, 16), dim3(256), 0, stream>>>(h0, hH, hL, hTa);

  int par = 0;
  for (int s = 0; s < NT_ - 1; ++s) {
    for (int st = 0; st < 4; ++st) {
      k_stage<<<dim3(512), dim3(512), 0, stream>>>(
          adjH, hH, hL, par ? hTb : hTa, par ? hTa : hTb, invdeg, W1TH, W1TL,
          W2TH, W2TL, W1, b1, b2, tg, s, st, out, accws);
      par ^= 1;
    }
  }
}

// Round 8
// 3107.798 us; speedup vs baseline: 1.4873x; 1.4873x over previous
//
#include <hip/hip_runtime.h>
#include <math.h>

// Problem dims
#define NB   16
#define NC   1024
#define ND   256
#define NT_  9
#define TDIM 32
#define BK   32

typedef _Float16 half8 __attribute__((ext_vector_type(8)));
typedef _Float16 half4v __attribute__((ext_vector_type(4)));
typedef float f32x4 __attribute__((ext_vector_type(4)));

#define GLL(gp, lp)                                                            \
  __builtin_amdgcn_global_load_lds(                                            \
      (const __attribute__((address_space(1))) void*)(gp),                     \
      (__attribute__((address_space(3))) void*)(lp), 16, 0, 0)

#define MFMA16(A, B, C) __builtin_amdgcn_mfma_f32_16x16x32_f16(A, B, C, 0, 0, 0)

// ---------------------------------------------------------------------------
__global__ __launch_bounds__(256) void k_copy_h0(const float* __restrict__ h0,
                                                 float* __restrict__ out) {
  size_t idx = (size_t)blockIdx.x * blockDim.x + threadIdx.x;
  size_t fe = idx * 4;
  size_t b = fe / ((size_t)NC * ND);
  size_t rem = fe % ((size_t)NC * ND);
  float4 v = *(const float4*)(h0 + fe);
  *(float4*)(out + (b * NT_) * (size_t)NC * ND + rem) = v;
}

// ---------------------------------------------------------------------------
__global__ __launch_bounds__(256) void k_deg(const float* __restrict__ adj,
                                             float* __restrict__ invdeg) {
  int wave = threadIdx.x >> 6;
  int lane = threadIdx.x & 63;
  int row = blockIdx.x * 4 + wave;
  const float* p = adj + (size_t)row * NC;
  float s = 0.f;
#pragma unroll
  for (int q = 0; q < 4; ++q) {
    float4 v = *(const float4*)(p + q * 256 + lane * 4);
    s += v.x + v.y + v.z + v.w;
  }
#pragma unroll
  for (int off = 32; off; off >>= 1) s += __shfl_down(s, off);
  if (lane == 0) invdeg[row] = 1.f / fmaxf(s, 1.f);
}

// ---------------------------------------------------------------------------
__global__ __launch_bounds__(256) void k_split_adj(const float* __restrict__ adj,
                                                   _Float16* __restrict__ aH) {
  size_t i4 = (size_t)blockIdx.x * 256 + threadIdx.x;
  float4 v = *(const float4*)(adj + i4 * 4);
  half4v h;
  h[0] = (_Float16)v.x; h[1] = (_Float16)v.y;
  h[2] = (_Float16)v.z; h[3] = (_Float16)v.w;
  *(half4v*)(aH + i4 * 4) = h;
}

// ---------------------------------------------------------------------------
__global__ __launch_bounds__(256) void k_split_w(const float* __restrict__ W1,
                                                 const float* __restrict__ W2,
                                                 _Float16* __restrict__ W1TH,
                                                 _Float16* __restrict__ W1TL,
                                                 _Float16* __restrict__ W2TH,
                                                 _Float16* __restrict__ W2TL) {
  int o = blockIdx.x * 256 + threadIdx.x;
  if (o < 256 * 512) {
    int n = o >> 9, k = o & 511;
    float v = W1[(size_t)k * ND + n];
    _Float16 h = (_Float16)v;
    W1TH[o] = h;
    W1TL[o] = (_Float16)(v - (float)h);
  } else {
    int o2 = o - 256 * 512;
    int n = o2 >> 8, k = o2 & 255;
    float v = W2[(size_t)k * ND + n];
    _Float16 h = (_Float16)v;
    W2TH[o2] = h;
    W2TL[o2] = (_Float16)(v - (float)h);
  }
}

// ---------------------------------------------------------------------------
// one-time: h0 -> hH/hL [b][c][d] + hT [b][d][c] (hi only)
__global__ __launch_bounds__(256) void k_htsplit(const float* __restrict__ src,
                                                 _Float16* __restrict__ hH,
                                                 _Float16* __restrict__ hL,
                                                 _Float16* __restrict__ hT) {
  __shared__ _Float16 tile[64][65];
  int b = blockIdx.z, c0 = blockIdx.x * 64, d0 = blockIdx.y * 64;
  int t = threadIdx.x;
#pragma unroll
  for (int it = 0; it < 16; ++it) {
    int e = it * 256 + t;
    int cl = e >> 6, dl = e & 63;
    float v = src[((size_t)b * NC + c0 + cl) * ND + d0 + dl];
    _Float16 h = (_Float16)v;
    _Float16 lo = (_Float16)(v - (float)h);
    size_t ni = ((size_t)b * NC + c0 + cl) * ND + d0 + dl;
    hH[ni] = h;
    hL[ni] = lo;
    tile[dl][cl] = h;
  }
  __syncthreads();
#pragma unroll
  for (int it = 0; it < 16; ++it) {
    int e = it * 256 + t;
    int dl = e >> 6, cl = e & 63;
    size_t ti = ((size_t)b * ND + d0 + dl) * NC + c0 + cl;
    hT[ti] = tile[dl][cl];
  }
}

// ---------------------------------------------------------------------------
// 256-thread staging: ROWS x 32 K-major rows -> plane-major chunks [g][row][8]
template <int ROWS>
__device__ __forceinline__ void stage_t(const _Float16* src, long stride,
                                        _Float16* dst, int wid, int lane) {
#pragma unroll
  for (int c = 0; c < ROWS / 64; ++c) {
    int nb = c * 256 + wid * 64;
    int n = nb + lane;
    int g = n / ROWS, r = n % ROWS;
    GLL(src + (size_t)r * stride + 8 * g, dst + (size_t)nb * 8);
  }
}

// ---------------------------------------------------------------------------
// GEMM1 (fp16 1-product): agg[b] = diag(invdeg[b]) * (adjH[b] @ h[b])
// 128x64 tile, dbuf 24KB, grid 512 flat with XCD-grouping swizzle.
__global__ __launch_bounds__(256) void k_agg(const _Float16* __restrict__ adjH,
                                             const _Float16* __restrict__ hT,
                                             const float* __restrict__ invdeg,
                                             _Float16* __restrict__ aggH) {
  int p = blockIdx.x;
  int xcd = p & 7, slot = p >> 3;
  int m_t = slot & 7;
  int g4 = xcd + 8 * (slot >> 3);
  int n_t = g4 & 3;
  int b = g4 >> 2;
  const int m0 = m_t * 128;
  const int n0 = n_t * 64;
  __shared__ __align__(16) _Float16 As[2][128 * BK];
  __shared__ __align__(16) _Float16 Bs[2][64 * BK];
  const int tid = threadIdx.x;
  const int lane = tid & 63, wid = tid >> 6;
  const int wm = wid >> 1, wn = wid & 1;
  const int g = lane >> 4, r = lane & 15;
  f32x4 acc[4][2] = {};
  const _Float16* A = adjH + (size_t)b * NC * NC + (size_t)m0 * NC;
  const _Float16* Bp = hT + (size_t)b * ND * NC + (size_t)n0 * NC;
  stage_t<128>(A, NC, As[0], wid, lane);
  stage_t<64>(Bp, NC, Bs[0], wid, lane);
  __syncthreads();
  for (int t = 0; t < 32; ++t) {
    int cur = t & 1;
    if (t + 1 < 32) {
      int k0 = (t + 1) * BK;
      stage_t<128>(A + k0, NC, As[cur ^ 1], wid, lane);
      stage_t<64>(Bp + k0, NC, Bs[cur ^ 1], wid, lane);
    }
    half8 Af[4], Bf[2];
#pragma unroll
    for (int i = 0; i < 4; ++i)
      Af[i] = ((const half8*)As[cur])[g * 128 + wm * 64 + i * 16 + r];
#pragma unroll
    for (int j = 0; j < 2; ++j)
      Bf[j] = ((const half8*)Bs[cur])[g * 64 + wn * 32 + j * 16 + r];
#pragma unroll
    for (int i = 0; i < 4; ++i)
#pragma unroll
      for (int j = 0; j < 2; ++j) acc[i][j] = MFMA16(Af[i], Bf[j], acc[i][j]);
    __syncthreads();
  }
  int rg = g * 4;
#pragma unroll
  for (int i = 0; i < 4; ++i) {
#pragma unroll
    for (int j = 0; j < 2; ++j) {
      int col = n0 + wn * 32 + j * 16 + r;
#pragma unroll
      for (int q = 0; q < 4; ++q) {
        int m = m0 + wm * 64 + i * 16 + rg + q;
        float v = acc[i][j][q] * invdeg[b * NC + m];
        aggH[((size_t)b * NC + m) * ND + col] = (_Float16)v;
      }
    }
  }
}

// ---------------------------------------------------------------------------
// GEMM2: u = tanh([h | agg] @ W1[0:512] + b1eff), uH only.
// 64x64 tile, dbuf 32KB, grid (256,4) = 4 blocks/CU. h: 3p, agg: 2p (hi).
__global__ __launch_bounds__(256) void k_mlp1(const _Float16* __restrict__ hH,
                                              const _Float16* __restrict__ hL,
                                              const _Float16* __restrict__ aggH,
                                              const _Float16* __restrict__ W1TH,
                                              const _Float16* __restrict__ W1TL,
                                              const float* __restrict__ W1,
                                              const float* __restrict__ b1,
                                              const float* __restrict__ tg,
                                              int step, int stage,
                                              _Float16* __restrict__ uH) {
  const int m0 = blockIdx.x * 64;
  const int n0 = blockIdx.y * 64;
  const int b = m0 >> 10, c0 = m0 & 1023;
  __shared__ __align__(16) _Float16 AsH[2][64 * BK];
  __shared__ __align__(16) _Float16 AsL[2][64 * BK];
  __shared__ __align__(16) _Float16 BsH[2][64 * BK];
  __shared__ __align__(16) _Float16 BsL[2][64 * BK];
  __shared__ float te_s[TDIM];
  __shared__ float b1s[64];
  const int tid = threadIdx.x;
  const int lane = tid & 63, wid = tid >> 6;
  const int wm = wid >> 1, wn = wid & 1;
  const int g = lane >> 4, r = lane & 15;
  f32x4 acc[2][2] = {};
  const size_t abase = ((size_t)b * NC + c0) * ND;
  // prologue: tile0 + time embedding
  stage_t<64>(hH + abase, ND, AsH[0], wid, lane);
  stage_t<64>(hL + abase, ND, AsL[0], wid, lane);
  stage_t<64>(W1TH + (size_t)n0 * 512, 512, BsH[0], wid, lane);
  stage_t<64>(W1TL + (size_t)n0 * 512, 512, BsL[0], wid, lane);
  if (tid < 16) {
    float t0 = tg[step], t1 = tg[step + 1];
    float frac = (stage == 0) ? 0.f : ((stage == 3) ? 1.f : 0.5f);
    float t = t0 + frac * (t1 - t0);
    float f = expf(-logf(10000.f) * (float)tid / 16.f);
    te_s[tid] = sinf(t * f);
    te_s[tid + 16] = cosf(t * f);
  }
  __syncthreads();
  if (tid < 64) {
    int col = n0 + tid;
    float s = b1[col];
#pragma unroll
    for (int q = 0; q < TDIM; ++q)
      s = fmaf(te_s[q], W1[(size_t)(512 + q) * ND + col], s);
    b1s[tid] = s;
  }
  for (int t = 0; t < 16; ++t) {
    int cur = t & 1;
    if (t + 1 < 16) {
      int k0 = (t + 1) * BK;
      if (k0 < 256) {
        stage_t<64>(hH + abase + k0, ND, AsH[cur ^ 1], wid, lane);
        stage_t<64>(hL + abase + k0, ND, AsL[cur ^ 1], wid, lane);
      } else {
        stage_t<64>(aggH + abase + (k0 - 256), ND, AsH[cur ^ 1], wid, lane);
      }
      stage_t<64>(W1TH + (size_t)n0 * 512 + k0, 512, BsH[cur ^ 1], wid, lane);
      stage_t<64>(W1TL + (size_t)n0 * 512 + k0, 512, BsL[cur ^ 1], wid, lane);
    }
    const bool hasL = (t < 8);
    half8 AH[2], AL[2], BH[2], BL[2];
#pragma unroll
    for (int i = 0; i < 2; ++i) {
      int ch = g * 64 + wm * 32 + i * 16 + r;
      AH[i] = ((const half8*)AsH[cur])[ch];
      AL[i] = ((const half8*)AsL[cur])[ch];
    }
#pragma unroll
    for (int j = 0; j < 2; ++j) {
      int ch = g * 64 + wn * 32 + j * 16 + r;
      BH[j] = ((const half8*)BsH[cur])[ch];
      BL[j] = ((const half8*)BsL[cur])[ch];
    }
#pragma unroll
    for (int i = 0; i < 2; ++i)
#pragma unroll
      for (int j = 0; j < 2; ++j) {
        acc[i][j] = MFMA16(AH[i], BH[j], acc[i][j]);
        acc[i][j] = MFMA16(AH[i], BL[j], acc[i][j]);
        if (hasL) acc[i][j] = MFMA16(AL[i], BH[j], acc[i][j]);
      }
    __syncthreads();
  }
  int rg = g * 4;
#pragma unroll
  for (int i = 0; i < 2; ++i) {
#pragma unroll
    for (int j = 0; j < 2; ++j) {
      int cl = wn * 32 + j * 16 + r;
#pragma unroll
      for (int q = 0; q < 4; ++q) {
        int m = m0 + wm * 32 + i * 16 + rg + q;
        float v = tanhf(acc[i][j][q] + b1s[cl]);
        uH[(size_t)m * ND + n0 + cl] = (_Float16)v;
      }
    }
  }
}

// ---------------------------------------------------------------------------
// GEMM3 (2-product) + RK4 epilogue. 64x64 tile, dbuf 24KB, grid (256,4).
__global__ __launch_bounds__(256) void k_mlp2(const _Float16* __restrict__ uH,
                                              const _Float16* __restrict__ W2TH,
                                              const _Float16* __restrict__ W2TL,
                                              const float* __restrict__ b2,
                                              const float* __restrict__ tg,
                                              int step, int stage,
                                              float* __restrict__ out,
                                              float* __restrict__ accws,
                                              _Float16* __restrict__ hH,
                                              _Float16* __restrict__ hL,
                                              _Float16* __restrict__ hT) {
  const int m0 = blockIdx.x * 64;
  const int n0 = blockIdx.y * 64;
  __shared__ __align__(16) _Float16 As[2][64 * BK];
  __shared__ __align__(16) _Float16 BsH[2][64 * BK];
  __shared__ __align__(16) _Float16 BsL[2][64 * BK];
  const int tid = threadIdx.x;
  const int lane = tid & 63, wid = tid >> 6;
  const int wm = wid >> 1, wn = wid & 1;
  const int g = lane >> 4, r = lane & 15;
  f32x4 acc[2][2] = {};
  stage_t<64>(uH + (size_t)m0 * ND, ND, As[0], wid, lane);
  stage_t<64>(W2TH + (size_t)n0 * ND, ND, BsH[0], wid, lane);
  stage_t<64>(W2TL + (size_t)n0 * ND, ND, BsL[0], wid, lane);
  __syncthreads();
  for (int t = 0; t < 8; ++t) {
    int cur = t & 1;
    if (t + 1 < 8) {
      int k0 = (t + 1) * BK;
      stage_t<64>(uH + (size_t)m0 * ND + k0, ND, As[cur ^ 1], wid, lane);
      stage_t<64>(W2TH + (size_t)n0 * ND + k0, ND, BsH[cur ^ 1], wid, lane);
      stage_t<64>(W2TL + (size_t)n0 * ND + k0, ND, BsL[cur ^ 1], wid, lane);
    }
    half8 Af[2], BH[2], BL[2];
#pragma unroll
    for (int i = 0; i < 2; ++i)
      Af[i] = ((const half8*)As[cur])[g * 64 + wm * 32 + i * 16 + r];
#pragma unroll
    for (int j = 0; j < 2; ++j) {
      int ch = g * 64 + wn * 32 + j * 16 + r;
      BH[j] = ((const half8*)BsH[cur])[ch];
      BL[j] = ((const half8*)BsL[cur])[ch];
    }
#pragma unroll
    for (int i = 0; i < 2; ++i)
#pragma unroll
      for (int j = 0; j < 2; ++j) {
        acc[i][j] = MFMA16(Af[i], BH[j], acc[i][j]);
        acc[i][j] = MFMA16(Af[i], BL[j], acc[i][j]);
      }
    __syncthreads();
  }
  const float t0 = tg[step], t1 = tg[step + 1];
  const float dt = t1 - t0;
  const float cs = (stage == 2) ? dt : 0.5f * dt;
  int rg = g * 4;
#pragma unroll
  for (int i = 0; i < 2; ++i) {
#pragma unroll
    for (int j = 0; j < 2; ++j) {
      int col = n0 + wn * 32 + j * 16 + r;
      float bb2 = b2[col];
      int mbase = m0 + wm * 32 + i * 16 + rg;  // multiple of 4, same batch
      int b = mbase >> 10, ii0 = mbase & 1023;
      size_t hrow = (((size_t)b * NT_ + step) * NC + ii0) * (size_t)ND + col;
      size_t wrow = (size_t)mbase * ND + col;
      float val[4];
#pragma unroll
      for (int q = 0; q < 4; ++q) {
        float f = acc[i][j][q] + bb2;
        float hb = out[hrow + (size_t)q * ND];
        size_t widx = wrow + (size_t)q * ND;
        if (stage == 0) {
          accws[widx] = f;
          val[q] = hb + cs * f;
        } else if (stage == 3) {
          float hn = hb + (dt / 6.f) * (accws[widx] + f);
          out[hrow + (size_t)NC * ND + (size_t)q * ND] = hn;  // traj[:,step+1]
          val[q] = hn;
        } else {
          accws[widx] += 2.f * f;
          val[q] = hb + cs * f;
        }
      }
      half4v th;
#pragma unroll
      for (int q = 0; q < 4; ++q) {
        _Float16 hh = (_Float16)val[q];
        th[q] = hh;
        size_t ni = ((size_t)b * NC + ii0 + q) * ND + col;
        hH[ni] = hh;
        hL[ni] = (_Float16)(val[q] - (float)hh);
      }
      size_t trow = ((size_t)b * ND + col) * NC + ii0;
      *(half4v*)(hT + trow) = th;
    }
  }
}

// ---------------------------------------------------------------------------
extern "C" void kernel_launch(void* const* d_in, const int* in_sizes, int n_in,
                              void* d_out, int out_size, void* d_ws, size_t ws_size,
                              hipStream_t stream) {
  const float* h0 = (const float*)d_in[0];
  const float* tg = (const float*)d_in[1];
  const float* adj = (const float*)d_in[2];
  const float* W1 = (const float*)d_in[3];
  const float* b1 = (const float*)d_in[4];
  const float* W2 = (const float*)d_in[5];
  const float* b2 = (const float*)d_in[6];
  float* out = (float*)d_out;

  const size_t CD = (size_t)NC * ND;  // 262144
  char* w = (char*)d_ws;
  float* invdeg = (float*)w;     w += (size_t)16384 * 4;
  float* accws = (float*)w;      w += (size_t)NB * CD * 4;
  _Float16* adjH = (_Float16*)w; w += (size_t)NB * NC * NC * 2;
  _Float16* hH = (_Float16*)w;   w += (size_t)NB * CD * 2;
  _Float16* hL = (_Float16*)w;   w += (size_t)NB * CD * 2;
  _Float16* hT = (_Float16*)w;   w += (size_t)NB * CD * 2;
  _Float16* aggH = (_Float16*)w; w += (size_t)NB * CD * 2;
  _Float16* uH = (_Float16*)w;   w += (size_t)NB * CD * 2;
  _Float16* W1TH = (_Float16*)w; w += (size_t)256 * 512 * 2;
  _Float16* W1TL = (_Float16*)w; w += (size_t)256 * 512 * 2;
  _Float16* W2TH = (_Float16*)w; w += (size_t)256 * 256 * 2;
  _Float16* W2TL = (_Float16*)w; w += (size_t)256 * 256 * 2;

  k_copy_h0<<<dim3(4096), dim3(256), 0, stream>>>(h0, out);
  k_deg<<<dim3(4096), dim3(256), 0, stream>>>(adj, invdeg);
  k_split_adj<<<dim3(16384), dim3(256), 0, stream>>>(adj, adjH);
  k_split_w<<<dim3(768), dim3(256), 0, stream>>>(W1, W2, W1TH, W1TL, W2TH, W2TL);
  k_htsplit<<<dim3(16, 4, 16), dim3(256), 0, stream>>>(h0, hH, hL, hT);

  for (int s = 0; s < NT_ - 1; ++s) {
    for (int st = 0; st < 4; ++st) {
      k_agg<<<dim3(512), dim3(256), 0, stream>>>(adjH, hT, invdeg, aggH);
      k_mlp1<<<dim3(256, 4), dim3(256), 0, stream>>>(hH, hL, aggH, W1TH, W1TL,
                                                     W1, b1, tg, s, st, uH);
      k_mlp2<<<dim3(256, 4), dim3(256), 0, stream>>>(uH, W2TH, W2TL, b2, tg, s, st,
                                                     out, accws, hH, hL, hT);
    }
  }
}

// Round 9
// 2836.095 us; speedup vs baseline: 1.6298x; 1.0958x over previous
//
#include <hip/hip_runtime.h>
#include <math.h>

// Problem dims
#define NB   16
#define NC   1024
#define ND   256
#define NT_  9
#define TDIM 32

typedef _Float16 half8 __attribute__((ext_vector_type(8)));
typedef _Float16 half4v __attribute__((ext_vector_type(4)));
typedef float f32x4 __attribute__((ext_vector_type(4)));

#define GLL(gp, lp)                                                            \
  __builtin_amdgcn_global_load_lds(                                            \
      (const __attribute__((address_space(1))) void*)(gp),                     \
      (__attribute__((address_space(3))) void*)(lp), 16, 0, 0)

#define MFMA16(A, B, C) __builtin_amdgcn_mfma_f32_16x16x32_f16(A, B, C, 0, 0, 0)

// ---------------------------------------------------------------------------
__global__ __launch_bounds__(256) void k_copy_h0(const float* __restrict__ h0,
                                                 float* __restrict__ out) {
  size_t idx = (size_t)blockIdx.x * blockDim.x + threadIdx.x;
  size_t fe = idx * 4;
  size_t b = fe / ((size_t)NC * ND);
  size_t rem = fe % ((size_t)NC * ND);
  float4 v = *(const float4*)(h0 + fe);
  *(float4*)(out + (b * NT_) * (size_t)NC * ND + rem) = v;
}

// ---------------------------------------------------------------------------
__global__ __launch_bounds__(256) void k_deg(const float* __restrict__ adj,
                                             float* __restrict__ invdeg) {
  int wave = threadIdx.x >> 6;
  int lane = threadIdx.x & 63;
  int row = blockIdx.x * 4 + wave;
  const float* p = adj + (size_t)row * NC;
  float s = 0.f;
#pragma unroll
  for (int q = 0; q < 4; ++q) {
    float4 v = *(const float4*)(p + q * 256 + lane * 4);
    s += v.x + v.y + v.z + v.w;
  }
#pragma unroll
  for (int off = 32; off; off >>= 1) s += __shfl_down(s, off);
  if (lane == 0) invdeg[row] = 1.f / fmaxf(s, 1.f);
}

// ---------------------------------------------------------------------------
__global__ __launch_bounds__(256) void k_split_adj(const float* __restrict__ adj,
                                                   _Float16* __restrict__ aH) {
  size_t i4 = (size_t)blockIdx.x * 256 + threadIdx.x;
  float4 v = *(const float4*)(adj + i4 * 4);
  half4v h;
  h[0] = (_Float16)v.x; h[1] = (_Float16)v.y;
  h[2] = (_Float16)v.z; h[3] = (_Float16)v.w;
  *(half4v*)(aH + i4 * 4) = h;
}

// ---------------------------------------------------------------------------
// W1[0:512]^T, W2^T -> fp16 hi only (W1TH [256][512], W2TH [256][256])
__global__ __launch_bounds__(256) void k_split_w(const float* __restrict__ W1,
                                                 const float* __restrict__ W2,
                                                 _Float16* __restrict__ W1TH,
                                                 _Float16* __restrict__ W2TH) {
  int o = blockIdx.x * 256 + threadIdx.x;
  if (o < 256 * 512) {
    int n = o >> 9, k = o & 511;
    W1TH[o] = (_Float16)W1[(size_t)k * ND + n];
  } else {
    int o2 = o - 256 * 512;
    int n = o2 >> 8, k = o2 & 255;
    W2TH[o2] = (_Float16)W2[(size_t)k * ND + n];
  }
}

// ---------------------------------------------------------------------------
// one-time: h0 -> hH/hL [b][c][d] + hT [b][d][c] (hi only)
__global__ __launch_bounds__(256) void k_htsplit(const float* __restrict__ src,
                                                 _Float16* __restrict__ hH,
                                                 _Float16* __restrict__ hL,
                                                 _Float16* __restrict__ hT) {
  __shared__ _Float16 tile[64][65];
  int b = blockIdx.z, c0 = blockIdx.x * 64, d0 = blockIdx.y * 64;
  int t = threadIdx.x;
#pragma unroll
  for (int it = 0; it < 16; ++it) {
    int e = it * 256 + t;
    int cl = e >> 6, dl = e & 63;
    float v = src[((size_t)b * NC + c0 + cl) * ND + d0 + dl];
    _Float16 h = (_Float16)v;
    _Float16 lo = (_Float16)(v - (float)h);
    size_t ni = ((size_t)b * NC + c0 + cl) * ND + d0 + dl;
    hH[ni] = h;
    hL[ni] = lo;
    tile[dl][cl] = h;
  }
  __syncthreads();
#pragma unroll
  for (int it = 0; it < 16; ++it) {
    int e = it * 256 + t;
    int dl = e >> 6, cl = e & 63;
    size_t ti = ((size_t)b * ND + d0 + dl) * NC + c0 + cl;
    hT[ti] = tile[dl][cl];
  }
}

// ---------------------------------------------------------------------------
// k_stage: one fused RK4 stage. grid 512 (XCD-swizzled), 512 thr = 8 waves,
// tile 32 rows x 256 cols; wave-tile 32x32 (2x2 frags). All operands in LDS,
// all global reads via global_load_lds, 2-barrier-per-step schedule.
// phase0 (K=1024, 1p): agg = invdeg * adj@h        -> aggS (LDS)
// phaseA (K=512): u = tanh([h|agg]@W1hi + b1eff)   -> uS (LDS, aliases aggS)
//                 h-half 2p (hH,hL x W1hi), agg-half 1p
// phaseB (K=256, 1p): f = u@W2hi + b2
// epilogue: RK4 update; hH/hL in place, hT ping-pong, traj out.
__global__ __launch_bounds__(512, 4) void k_stage(
    const _Float16* __restrict__ adjH,
    _Float16* __restrict__ hH, _Float16* __restrict__ hL,
    const _Float16* __restrict__ hTr, _Float16* __restrict__ hTw,
    const float* __restrict__ invdeg,
    const _Float16* __restrict__ W1TH, const _Float16* __restrict__ W2TH,
    const float* __restrict__ W1, const float* __restrict__ b1,
    const float* __restrict__ b2, const float* __restrict__ tg,
    int step, int stage, float* __restrict__ out, float* __restrict__ accws) {
  __shared__ __align__(16) _Float16 Bs[256 * 32];  // 16 KB B-panel
  __shared__ __align__(16) _Float16 AsH[32 * 32];  // 2 KB
  __shared__ __align__(16) _Float16 AsL[32 * 32];  // 2 KB
  __shared__ __align__(16) _Float16 POOL[8192];    // 16 KB aggS -> uS
  __shared__ float te_s[TDIM];
  __shared__ float b1s[256];
  _Float16* aggS = POOL;
  _Float16* uS = POOL;  // alias; disjoint lifetimes

  const int tid = threadIdx.x;
  const int lane = tid & 63, wid = tid >> 6;  // 8 waves, all along N
  const int g = lane >> 4, r = lane & 15, rg = (lane >> 4) * 4;
  // swizzle: batch b's 32 blocks share id mod 8 -> one XCD
  const int p = blockIdx.x;
  const int b = ((p >> 3) >> 5) * 8 + (p & 7);
  const int mq = (p >> 3) & 31;

  const _Float16* adjA = adjH + ((size_t)b * NC + mq * 32) * NC;  // 32 rows
  const _Float16* B0 = hTr + (size_t)b * ND * NC;                 // 256 rows
  const size_t abase = ((size_t)b * NC + mq * 32) * ND;

  f32x4 acc[2][2] = {};

// B-panel staging: 256 rows x 32 halves (row-stride STRIDE) -> chunks [gk][n][8]
#define STAGE_B(SRC, STRIDE, K0)                                               \
  do {                                                                         \
    _Pragma("unroll") for (int c = 0; c < 2; ++c) {                            \
      int e = c * 512 + tid;                                                   \
      GLL((SRC) + (size_t)(e & 255) * (STRIDE) + (e >> 8) * 8 + (K0),          \
          Bs + (size_t)e * 8);                                                 \
    }                                                                          \
  } while (0)

  // ---- prologue: time embedding + b1eff ----
  if (tid < 16) {
    float t0 = tg[step], t1 = tg[step + 1];
    float frac = (stage == 0) ? 0.f : ((stage == 3) ? 1.f : 0.5f);
    float t = t0 + frac * (t1 - t0);
    float f = expf(-logf(10000.f) * (float)tid / 16.f);
    te_s[tid] = sinf(t * f);
    te_s[tid + 16] = cosf(t * f);
  }
  __syncthreads();
  if (tid < 256) {
    float s = b1[tid];
#pragma unroll
    for (int q = 0; q < TDIM; ++q)
      s = fmaf(te_s[q], W1[(size_t)(512 + q) * ND + tid], s);
    b1s[tid] = s;
  }

  // ---- phase 0: K=1024, 1-product (adj-hi x hT-hi) ----
  for (int t = 0; t < 32; ++t) {
    int k0 = t * 32;
    if (tid < 128)
      GLL(adjA + (size_t)(tid & 31) * NC + (tid >> 5) * 8 + k0,
          AsH + (size_t)tid * 8);
    STAGE_B(B0, NC, k0);
    __syncthreads();
    half8 Af[2], Bf[2];
#pragma unroll
    for (int i = 0; i < 2; ++i)
      Af[i] = ((const half8*)AsH)[g * 32 + i * 16 + r];
#pragma unroll
    for (int j = 0; j < 2; ++j)
      Bf[j] = ((const half8*)Bs)[g * 256 + wid * 32 + j * 16 + r];
#pragma unroll
    for (int i = 0; i < 2; ++i)
#pragma unroll
      for (int j = 0; j < 2; ++j) acc[i][j] = MFMA16(Af[i], Bf[j], acc[i][j]);
    __syncthreads();
  }
  // phase0 epilogue: invdeg scale -> aggS (hi)
#pragma unroll
  for (int i = 0; i < 2; ++i) {
#pragma unroll
    for (int j = 0; j < 2; ++j) {
      int d = wid * 32 + j * 16 + r;
#pragma unroll
      for (int q = 0; q < 4; ++q) {
        int lr = i * 16 + rg + q;
        float v = acc[i][j][q] * invdeg[b * NC + mq * 32 + lr];
        aggS[((d >> 3) * 32 + lr) * 8 + (d & 7)] = (_Float16)v;
      }
      acc[i][j] = (f32x4){0.f, 0.f, 0.f, 0.f};
    }
  }
  // ---- phase A: K=512 over [h | agg]; B = W1T-hi ----
  for (int t = 0; t < 16; ++t) {
    int k0 = t * 32;
    if (t < 8) {
      if (tid < 128)
        GLL(hH + abase + (size_t)(tid & 31) * ND + (tid >> 5) * 8 + k0,
            AsH + (size_t)tid * 8);
      else if (tid < 256)
        GLL(hL + abase + (size_t)((tid - 128) & 31) * ND + ((tid - 128) >> 5) * 8 + k0,
            AsL + (size_t)(tid - 128) * 8);
    }
    STAGE_B(W1TH, 512, k0);
    __syncthreads();
    half8 AH[2], AL[2], Bf[2];
    const bool hasL = (t < 8);
    if (hasL) {
#pragma unroll
      for (int i = 0; i < 2; ++i) {
        AH[i] = ((const half8*)AsH)[g * 32 + i * 16 + r];
        AL[i] = ((const half8*)AsL)[g * 32 + i * 16 + r];
      }
    } else {
#pragma unroll
      for (int i = 0; i < 2; ++i)
        AH[i] = ((const half8*)aggS)[((t - 8) * 4 + g) * 32 + i * 16 + r];
    }
#pragma unroll
    for (int j = 0; j < 2; ++j)
      Bf[j] = ((const half8*)Bs)[g * 256 + wid * 32 + j * 16 + r];
#pragma unroll
    for (int i = 0; i < 2; ++i)
#pragma unroll
      for (int j = 0; j < 2; ++j) {
        acc[i][j] = MFMA16(AH[i], Bf[j], acc[i][j]);
        if (hasL) acc[i][j] = MFMA16(AL[i], Bf[j], acc[i][j]);
      }
    __syncthreads();
  }
  // ---- transition: uS = tanh(acc + b1eff) (aliases dead aggS) ----
#pragma unroll
  for (int i = 0; i < 2; ++i) {
#pragma unroll
    for (int j = 0; j < 2; ++j) {
      int col = wid * 32 + j * 16 + r;
#pragma unroll
      for (int q = 0; q < 4; ++q) {
        int row = i * 16 + rg + q;
        float v = tanhf(acc[i][j][q] + b1s[col]);
        uS[((col >> 3) * 32 + row) * 8 + (col & 7)] = (_Float16)v;
      }
      acc[i][j] = (f32x4){0.f, 0.f, 0.f, 0.f};
    }
  }
  __syncthreads();
  // ---- phase B: K=256 over u; B = W2T-hi ----
  for (int t = 0; t < 8; ++t) {
    int k0 = t * 32;
    STAGE_B(W2TH, 256, k0);
    __syncthreads();
    half8 Af[2], Bf[2];
#pragma unroll
    for (int i = 0; i < 2; ++i)
      Af[i] = ((const half8*)uS)[(t * 4 + g) * 32 + i * 16 + r];
#pragma unroll
    for (int j = 0; j < 2; ++j)
      Bf[j] = ((const half8*)Bs)[g * 256 + wid * 32 + j * 16 + r];
#pragma unroll
    for (int i = 0; i < 2; ++i)
#pragma unroll
      for (int j = 0; j < 2; ++j) acc[i][j] = MFMA16(Af[i], Bf[j], acc[i][j]);
    __syncthreads();
  }
  // ---- RK4 epilogue ----
  const float t0 = tg[step], t1 = tg[step + 1];
  const float dt = t1 - t0;
  const float cs = (stage == 2) ? dt : 0.5f * dt;
#pragma unroll
  for (int i = 0; i < 2; ++i) {
#pragma unroll
    for (int j = 0; j < 2; ++j) {
      int col = wid * 32 + j * 16 + r;
      float bb2 = b2[col];
      int ii0 = mq * 32 + i * 16 + rg;  // row in batch, multiple of 4
      size_t hrow = (((size_t)b * NT_ + step) * NC + ii0) * (size_t)ND + col;
      size_t wrow = ((size_t)b * NC + ii0) * (size_t)ND + col;
      float val[4];
#pragma unroll
      for (int q = 0; q < 4; ++q) {
        float f = acc[i][j][q] + bb2;
        float hb = out[hrow + (size_t)q * ND];
        size_t widx = wrow + (size_t)q * ND;
        if (stage == 0) {
          accws[widx] = f;
          val[q] = hb + cs * f;
        } else if (stage == 3) {
          float hn = hb + (dt / 6.f) * (accws[widx] + f);
          out[hrow + (size_t)NC * ND + (size_t)q * ND] = hn;  // traj[:,step+1]
          val[q] = hn;
        } else {
          accws[widx] += 2.f * f;
          val[q] = hb + cs * f;
        }
      }
      half4v th;
#pragma unroll
      for (int q = 0; q < 4; ++q) {
        _Float16 hh = (_Float16)val[q];
        th[q] = hh;
        size_t ni = ((size_t)b * NC + ii0 + q) * ND + col;
        hH[ni] = hh;
        hL[ni] = (_Float16)(val[q] - (float)hh);
      }
      size_t trow = ((size_t)b * ND + col) * NC + ii0;
      *(half4v*)(hTw + trow) = th;
    }
  }
#undef STAGE_B
}

// ---------------------------------------------------------------------------
extern "C" void kernel_launch(void* const* d_in, const int* in_sizes, int n_in,
                              void* d_out, int out_size, void* d_ws, size_t ws_size,
                              hipStream_t stream) {
  const float* h0 = (const float*)d_in[0];
  const float* tg = (const float*)d_in[1];
  const float* adj = (const float*)d_in[2];
  const float* W1 = (const float*)d_in[3];
  const float* b1 = (const float*)d_in[4];
  const float* W2 = (const float*)d_in[5];
  const float* b2 = (const float*)d_in[6];
  float* out = (float*)d_out;

  const size_t CD = (size_t)NC * ND;  // 262144
  char* w = (char*)d_ws;
  float* invdeg = (float*)w;     w += (size_t)16384 * 4;
  float* accws = (float*)w;      w += (size_t)NB * CD * 4;
  _Float16* adjH = (_Float16*)w; w += (size_t)NB * NC * NC * 2;
  _Float16* hH = (_Float16*)w;   w += (size_t)NB * CD * 2;
  _Float16* hL = (_Float16*)w;   w += (size_t)NB * CD * 2;
  _Float16* hTa = (_Float16*)w;  w += (size_t)NB * CD * 2;
  _Float16* hTb = (_Float16*)w;  w += (size_t)NB * CD * 2;
  _Float16* W1TH = (_Float16*)w; w += (size_t)256 * 512 * 2;
  _Float16* W2TH = (_Float16*)w; w += (size_t)256 * 256 * 2;

  k_copy_h0<<<dim3(4096), dim3(256), 0, stream>>>(h0, out);
  k_deg<<<dim3(4096), dim3(256), 0, stream>>>(adj, invdeg);
  k_split_adj<<<dim3(16384), dim3(256), 0, stream>>>(adj, adjH);
  k_split_w<<<dim3(768), dim3(256), 0, stream>>>(W1, W2, W1TH, W2TH);
  k_htsplit<<<dim3(16, 4, 16), dim3(256), 0, stream>>>(h0, hH, hL, hTa);

  int par = 0;
  for (int s = 0; s < NT_ - 1; ++s) {
    for (int st = 0; st < 4; ++st) {
      k_stage<<<dim3(512), dim3(512), 0, stream>>>(
          adjH, hH, hL, par ? hTb : hTa, par ? hTa : hTb, invdeg, W1TH, W2TH,
          W1, b1, b2, tg, s, st, out, accws);
      par ^= 1;
    }
  }
}